// Round 1
// baseline (487.408 us; speedup 1.0000x reference)
//
#include <hip/hip_runtime.h>
#include <hip/hip_bf16.h>

// Self-attention with softmax over the QUERY axis (dim=1):
//   Q=XWq^T K=XWk^T V=XWv^T ; s = QK^T/16 ; attn[:,q,k] = exp(s)/sum_q exp(s)
//   out = attn @ V
// B=4, S=4096, D=Q_DIM=256.

#define BATCH 4
#define SEQ 4096
#define DIM 256
#define ROWS (BATCH * SEQ)   // 16384

typedef __bf16 bf16x8 __attribute__((ext_vector_type(8)));
typedef float f32x4 __attribute__((ext_vector_type(4)));

__device__ __forceinline__ unsigned short f2b(float f) {
    union { float f; unsigned u; } v; v.f = f;
    unsigned u = v.u;
    u += 0x7FFFu + ((u >> 16) & 1u);   // RNE
    return (unsigned short)(u >> 16);
}

__device__ __forceinline__ float b2f(unsigned short h) {
    union { unsigned u; float f; } v; v.u = ((unsigned)h) << 16;
    return v.f;
}

// ---------------- cast f32 -> bf16 ----------------
__global__ void cast_f32_bf16(const float* __restrict__ in,
                              unsigned short* __restrict__ out, int n) {
    int i = blockIdx.x * blockDim.x + threadIdx.x;
    if (i < n) out[i] = f2b(in[i]);
}

// ---------------- GEMM: out = A(Mx256) * Bw(Nx256)^T, bf16 in/out ----------------
// B^T pattern: both fragments load contiguous bf16x8 from row-major [row][d].
__global__ __launch_bounds__(256) void gemm_bt(const unsigned short* __restrict__ A,
                                               const unsigned short* __restrict__ Bw,
                                               unsigned short* __restrict__ out,
                                               int M, int N, int transpose_out) {
    const int l = threadIdx.x & 63;
    const int w = threadIdx.x >> 6;
    const int wr = w >> 1, wc = w & 1;
    const int lr = l & 15, lk = l >> 4;
    const int rbase = blockIdx.x * 128 + wr * 64;
    const int cbase = blockIdx.y * 128 + wc * 64;

    f32x4 acc[4][4] = {};
#pragma unroll
    for (int d0 = 0; d0 < 256; d0 += 32) {
        bf16x8 a[4], b[4];
#pragma unroll
        for (int i = 0; i < 4; ++i)
            a[i] = *(const bf16x8*)(A + (size_t)(rbase + i * 16 + lr) * 256 + d0 + lk * 8);
#pragma unroll
        for (int j = 0; j < 4; ++j)
            b[j] = *(const bf16x8*)(Bw + (size_t)(cbase + j * 16 + lr) * 256 + d0 + lk * 8);
#pragma unroll
        for (int i = 0; i < 4; ++i)
#pragma unroll
            for (int j = 0; j < 4; ++j)
                acc[i][j] = __builtin_amdgcn_mfma_f32_16x16x32_bf16(a[i], b[j], acc[i][j], 0, 0, 0);
    }
#pragma unroll
    for (int i = 0; i < 4; ++i)
#pragma unroll
        for (int j = 0; j < 4; ++j)
#pragma unroll
            for (int r = 0; r < 4; ++r) {
                int row = rbase + i * 16 + lk * 4 + r;
                int col = cbase + j * 16 + lr;
                unsigned short v = f2b(acc[i][j][r]);
                if (!transpose_out) out[(size_t)row * N + col] = v;
                else                out[(size_t)col * M + row] = v;
            }
}

// ---------------- column-sum of exp(s/16): l[b][k] = sum_q exp(s[q,k]/16) --------
// grid: (32 k-tiles of 128, 2 q-chunks of 2048, 4 batches), block 256.
__global__ __launch_bounds__(256) void colsumexp(const unsigned short* __restrict__ Qb,
                                                 const unsigned short* __restrict__ Kb,
                                                 float* __restrict__ lsum) {
    const int l = threadIdx.x & 63;
    const int w = threadIdx.x >> 6;
    const int wr = w >> 1, wc = w & 1;
    const int lr = l & 15, lk = l >> 4;
    const int b = blockIdx.z;
    const int cbase = blockIdx.x * 128 + wc * 64;   // k columns
    const unsigned short* Q = Qb + (size_t)b * SEQ * 256;
    const unsigned short* K = Kb + (size_t)b * SEQ * 256;

    float csum[4] = {0.f, 0.f, 0.f, 0.f};
    for (int qi = 0; qi < 16; ++qi) {
        const int rbase = blockIdx.y * 2048 + qi * 128 + wr * 64;
        f32x4 acc[4][4] = {};
#pragma unroll
        for (int d0 = 0; d0 < 256; d0 += 32) {
            bf16x8 a[4], bb[4];
#pragma unroll
            for (int i = 0; i < 4; ++i)
                a[i] = *(const bf16x8*)(Q + (size_t)(rbase + i * 16 + lr) * 256 + d0 + lk * 8);
#pragma unroll
            for (int j = 0; j < 4; ++j)
                bb[j] = *(const bf16x8*)(K + (size_t)(cbase + j * 16 + lr) * 256 + d0 + lk * 8);
#pragma unroll
            for (int i = 0; i < 4; ++i)
#pragma unroll
                for (int j = 0; j < 4; ++j)
                    acc[i][j] = __builtin_amdgcn_mfma_f32_16x16x32_bf16(a[i], bb[j], acc[i][j], 0, 0, 0);
        }
#pragma unroll
        for (int j = 0; j < 4; ++j) {
            float s = 0.f;
#pragma unroll
            for (int i = 0; i < 4; ++i)
#pragma unroll
                for (int r = 0; r < 4; ++r)
                    s += expf(acc[i][j][r] * 0.0625f);
            csum[j] += s;
        }
    }
#pragma unroll
    for (int j = 0; j < 4; ++j) {
        float s = csum[j];
        s += __shfl_xor(s, 16, 64);
        s += __shfl_xor(s, 32, 64);
        if (lk == 0)
            atomicAdd(&lsum[(size_t)b * SEQ + cbase + j * 16 + lr], s);
    }
}

// ---------------- scale Vt rows by 1/l: Vt[v][b*S+k] *= 1/l[b*S+k] ----------------
__global__ void scale_vt(unsigned short* __restrict__ Vt,
                         const float* __restrict__ lsum, int n) {
    int i = blockIdx.x * blockDim.x + threadIdx.x;
    if (i >= n) return;
    int col = i & (ROWS - 1);            // ROWS = 16384, col = b*SEQ + k
    float rl = 1.0f / lsum[col];
    Vt[i] = f2b(b2f(Vt[i]) * rl);
}

// ---------------- PV: out[b,q,v] = sum_k exp(s[q,k]/16) * Vt'[v][k] ----------------
// grid: (32 q-tiles of 128, 2 v-tiles of 128, 4 batches), block 256.
__global__ __launch_bounds__(256) void pv_kernel(const unsigned short* __restrict__ Qb,
                                                 const unsigned short* __restrict__ Kb,
                                                 const unsigned short* __restrict__ Vt,
                                                 float* __restrict__ out) {
    __shared__ unsigned short P[128][72];   // pad 64 -> 72 (+16B) to break bank conflicts
    const int l = threadIdx.x & 63;
    const int w = threadIdx.x >> 6;
    const int wr = w >> 1, wc = w & 1;
    const int lr = l & 15, lk = l >> 4;
    const int b = blockIdx.z;
    const int qbase = blockIdx.x * 128;
    const int vbase = blockIdx.y * 128;
    const unsigned short* Q = Qb + (size_t)b * SEQ * 256;
    const unsigned short* K = Kb + (size_t)b * SEQ * 256;
    const unsigned short* V = Vt + (size_t)b * SEQ;   // Vt[v][ROWS], batch col slice

    f32x4 oacc[4][4] = {};
    for (int k0 = 0; k0 < SEQ; k0 += 64) {
        // phase 1: s-tile (128q x 64k); wave (wr,wc) covers 64q x 32k
        f32x4 sacc[4][2] = {};
#pragma unroll
        for (int d0 = 0; d0 < 256; d0 += 32) {
            bf16x8 a[4], bb[2];
#pragma unroll
            for (int i = 0; i < 4; ++i)
                a[i] = *(const bf16x8*)(Q + (size_t)(qbase + wr * 64 + i * 16 + lr) * 256 + d0 + lk * 8);
#pragma unroll
            for (int j = 0; j < 2; ++j)
                bb[j] = *(const bf16x8*)(K + (size_t)(k0 + wc * 32 + j * 16 + lr) * 256 + d0 + lk * 8);
#pragma unroll
            for (int i = 0; i < 4; ++i)
#pragma unroll
                for (int j = 0; j < 2; ++j)
                    sacc[i][j] = __builtin_amdgcn_mfma_f32_16x16x32_bf16(a[i], bb[j], sacc[i][j], 0, 0, 0);
        }
#pragma unroll
        for (int i = 0; i < 4; ++i)
#pragma unroll
            for (int j = 0; j < 2; ++j)
#pragma unroll
                for (int r = 0; r < 4; ++r) {
                    int row = wr * 64 + i * 16 + lk * 4 + r;
                    int col = wc * 32 + j * 16 + lr;
                    P[row][col] = f2b(expf(sacc[i][j][r] * 0.0625f));
                }
        __syncthreads();
        // phase 2: oacc += P(128x64) @ Vt'(64x128); wave (wr,wc) covers 64q x 64v
#pragma unroll
        for (int ks = 0; ks < 2; ++ks) {
            bf16x8 a[4], bb[4];
#pragma unroll
            for (int i = 0; i < 4; ++i)
                a[i] = *(const bf16x8*)(&P[wr * 64 + i * 16 + lr][ks * 32 + lk * 8]);
#pragma unroll
            for (int j = 0; j < 4; ++j)
                bb[j] = *(const bf16x8*)(V + (size_t)(vbase + wc * 64 + j * 16 + lr) * ROWS + k0 + ks * 32 + lk * 8);
#pragma unroll
            for (int i = 0; i < 4; ++i)
#pragma unroll
                for (int j = 0; j < 4; ++j)
                    oacc[i][j] = __builtin_amdgcn_mfma_f32_16x16x32_bf16(a[i], bb[j], oacc[i][j], 0, 0, 0);
        }
        __syncthreads();
    }
    float* O = out + (size_t)b * SEQ * 256;
#pragma unroll
    for (int i = 0; i < 4; ++i)
#pragma unroll
        for (int j = 0; j < 4; ++j)
#pragma unroll
            for (int r = 0; r < 4; ++r) {
                int row = qbase + wr * 64 + i * 16 + lk * 4 + r;
                int col = vbase + wc * 64 + j * 16 + lr;
                O[(size_t)row * 256 + col] = oacc[i][j][r];
            }
}

extern "C" void kernel_launch(void* const* d_in, const int* in_sizes, int n_in,
                              void* d_out, int out_size, void* d_ws, size_t ws_size,
                              hipStream_t stream) {
    const float* x  = (const float*)d_in[0];
    const float* wq = (const float*)d_in[1];
    const float* wk = (const float*)d_in[2];
    const float* wv = (const float*)d_in[3];
    float* out = (float*)d_out;

    char* ws = (char*)d_ws;
    unsigned short* Xb  = (unsigned short*)(ws + 0);
    unsigned short* Qb  = (unsigned short*)(ws + 8388608);
    unsigned short* Kb  = (unsigned short*)(ws + 16777216);
    unsigned short* Vt  = (unsigned short*)(ws + 25165824);
    unsigned short* Wqb = (unsigned short*)(ws + 33554432);
    unsigned short* Wkb = (unsigned short*)(ws + 33685504);
    unsigned short* Wvb = (unsigned short*)(ws + 33816576);
    float*          lsum = (float*)(ws + 33947648);

    const int n_x = ROWS * DIM;      // 4194304
    const int n_w = DIM * DIM;       // 65536

    cast_f32_bf16<<<(n_x + 255) / 256, 256, 0, stream>>>(x, Xb, n_x);
    cast_f32_bf16<<<(n_w + 255) / 256, 256, 0, stream>>>(wq, Wqb, n_w);
    cast_f32_bf16<<<(n_w + 255) / 256, 256, 0, stream>>>(wk, Wkb, n_w);
    cast_f32_bf16<<<(n_w + 255) / 256, 256, 0, stream>>>(wv, Wvb, n_w);

    dim3 gg(ROWS / 128, DIM / 128);   // (128, 2)
    gemm_bt<<<gg, 256, 0, stream>>>(Xb, Wqb, Qb, ROWS, DIM, 0);
    gemm_bt<<<gg, 256, 0, stream>>>(Xb, Wkb, Kb, ROWS, DIM, 0);
    gemm_bt<<<gg, 256, 0, stream>>>(Xb, Wvb, Vt, ROWS, DIM, 1);  // transposed store

    hipMemsetAsync(lsum, 0, (size_t)BATCH * SEQ * sizeof(float), stream);
    dim3 gs(SEQ / 128, 2, BATCH);     // (32, 2, 4)
    colsumexp<<<gs, 256, 0, stream>>>(Qb, Kb, lsum);

    scale_vt<<<(n_x + 255) / 256, 256, 0, stream>>>(Vt, lsum, n_x);

    dim3 gp(SEQ / 128, DIM / 128, BATCH);   // (32, 2, 4)
    pv_kernel<<<gp, 256, 0, stream>>>(Qb, Kb, Vt, out);
}

// Round 2
// 367.354 us; speedup vs baseline: 1.3268x; 1.3268x over previous
//
#include <hip/hip_runtime.h>
#include <hip/hip_bf16.h>

// Self-attention with softmax over the QUERY axis (dim=1):
//   Q=XWq^T K=XWk^T V=XWv^T ; s = QK^T/16 ; attn[:,q,k] = exp(s)/sum_q exp(s)
//   out = attn @ V
// B=4, S=4096, D=Q_DIM=256.
//
// Path A (ws >= ~168MB): materialize P=exp(s/16) bf16 in ws; PV = plain GEMM.
// Path B (fallback):     R1 flash-style recompute kernels.

#define BATCH 4
#define SEQ 4096
#define DIM 256
#define ROWS (BATCH * SEQ)   // 16384

typedef __bf16 bf16x8 __attribute__((ext_vector_type(8)));
typedef float f32x4 __attribute__((ext_vector_type(4)));

__device__ __forceinline__ unsigned short f2b(float f) {
    union { float f; unsigned u; } v; v.f = f;
    unsigned u = v.u;
    u += 0x7FFFu + ((u >> 16) & 1u);   // RNE
    return (unsigned short)(u >> 16);
}

__device__ __forceinline__ float b2f(unsigned short h) {
    union { unsigned u; float f; } v; v.u = ((unsigned)h) << 16;
    return v.f;
}

// ---------------- cast f32 -> bf16 ----------------
__global__ void cast_f32_bf16(const float* __restrict__ in,
                              unsigned short* __restrict__ out, int n) {
    int i = blockIdx.x * blockDim.x + threadIdx.x;
    if (i < n) out[i] = f2b(in[i]);
}

// ---------------- GEMM: out = A(Mx256) * Bw(Nx256)^T, bf16 in/out ----------------
__global__ __launch_bounds__(256) void gemm_bt(const unsigned short* __restrict__ A,
                                               const unsigned short* __restrict__ Bw,
                                               unsigned short* __restrict__ out,
                                               int M, int N, int transpose_out) {
    const int l = threadIdx.x & 63;
    const int w = threadIdx.x >> 6;
    const int wr = w >> 1, wc = w & 1;
    const int lr = l & 15, lk = l >> 4;
    const int rbase = blockIdx.x * 128 + wr * 64;
    const int cbase = blockIdx.y * 128 + wc * 64;

    f32x4 acc[4][4] = {};
#pragma unroll
    for (int d0 = 0; d0 < 256; d0 += 32) {
        bf16x8 a[4], b[4];
#pragma unroll
        for (int i = 0; i < 4; ++i)
            a[i] = *(const bf16x8*)(A + (size_t)(rbase + i * 16 + lr) * 256 + d0 + lk * 8);
#pragma unroll
        for (int j = 0; j < 4; ++j)
            b[j] = *(const bf16x8*)(Bw + (size_t)(cbase + j * 16 + lr) * 256 + d0 + lk * 8);
#pragma unroll
        for (int i = 0; i < 4; ++i)
#pragma unroll
            for (int j = 0; j < 4; ++j)
                acc[i][j] = __builtin_amdgcn_mfma_f32_16x16x32_bf16(a[i], b[j], acc[i][j], 0, 0, 0);
    }
#pragma unroll
    for (int i = 0; i < 4; ++i)
#pragma unroll
        for (int j = 0; j < 4; ++j)
#pragma unroll
            for (int r = 0; r < 4; ++r) {
                int row = rbase + i * 16 + lk * 4 + r;
                int col = cbase + j * 16 + lr;
                unsigned short v = f2b(acc[i][j][r]);
                if (!transpose_out) out[(size_t)row * N + col] = v;
                else                out[(size_t)col * M + row] = v;
            }
}

// ================= PATH A =================
// s-tile 128q x 128k; P=exp(s/16) -> ws (bf16, [b][q][k]); column partial sums
// -> atomicAdd lsum. grid (32 k, 32 q, 4 b), block 256.
__global__ __launch_bounds__(256) void sp_kernel(const unsigned short* __restrict__ Qb,
                                                 const unsigned short* __restrict__ Kb,
                                                 unsigned short* __restrict__ P,
                                                 float* __restrict__ lsum) {
    const int l = threadIdx.x & 63;
    const int w = threadIdx.x >> 6;
    const int wr = w >> 1, wc = w & 1;
    const int lr = l & 15, lk = l >> 4;
    const int b = blockIdx.z;
    const int kbase = blockIdx.x * 128 + wc * 64;
    const int qbase = blockIdx.y * 128 + wr * 64;
    const unsigned short* Q = Qb + (size_t)b * SEQ * 256;
    const unsigned short* K = Kb + (size_t)b * SEQ * 256;
    unsigned short* Pb = P + (size_t)b * SEQ * SEQ;

    f32x4 acc[4][4] = {};
#pragma unroll
    for (int d0 = 0; d0 < 256; d0 += 32) {
        bf16x8 a[4], bb[4];
#pragma unroll
        for (int i = 0; i < 4; ++i)
            a[i] = *(const bf16x8*)(Q + (size_t)(qbase + i * 16 + lr) * 256 + d0 + lk * 8);
#pragma unroll
        for (int j = 0; j < 4; ++j)
            bb[j] = *(const bf16x8*)(K + (size_t)(kbase + j * 16 + lr) * 256 + d0 + lk * 8);
#pragma unroll
        for (int i = 0; i < 4; ++i)
#pragma unroll
            for (int j = 0; j < 4; ++j)
                acc[i][j] = __builtin_amdgcn_mfma_f32_16x16x32_bf16(a[i], bb[j], acc[i][j], 0, 0, 0);
    }
#pragma unroll
    for (int j = 0; j < 4; ++j) {
        float cs = 0.f;
#pragma unroll
        for (int i = 0; i < 4; ++i)
#pragma unroll
            for (int r = 0; r < 4; ++r) {
                int row = qbase + i * 16 + lk * 4 + r;
                int col = kbase + j * 16 + lr;
                float v = __expf(acc[i][j][r] * 0.0625f);
                cs += v;
                Pb[(size_t)row * SEQ + col] = f2b(v);
            }
        cs += __shfl_xor(cs, 16, 64);
        cs += __shfl_xor(cs, 32, 64);
        if (lk == 0)
            atomicAdd(&lsum[(size_t)b * SEQ + kbase + j * 16 + lr], cs);
    }
}

// scale Vt rows by 1/l: Vt[v][b*S+k] *= 1/l[b*S+k]
__global__ void scale_vt(unsigned short* __restrict__ Vt,
                         const float* __restrict__ lsum, int n) {
    int i = blockIdx.x * blockDim.x + threadIdx.x;
    if (i >= n) return;
    int col = i & (ROWS - 1);
    float rl = 1.0f / lsum[col];
    Vt[i] = f2b(b2f(Vt[i]) * rl);
}

// PV GEMM: out[b,q,v] = sum_k P[b,q,k] * Vts[v][b*S+k]
// tile 128q x 128v, 512 thr = 8 waves (4x2), k-step 32, 128 iters.
__global__ __launch_bounds__(512) void pv_gemm(const unsigned short* __restrict__ P,
                                               const unsigned short* __restrict__ Vt,
                                               float* __restrict__ out) {
    const int l = threadIdx.x & 63;
    const int w = threadIdx.x >> 6;
    const int wr = w >> 1, wc = w & 1;
    const int lr = l & 15, lk = l >> 4;
    const int b = blockIdx.z;
    const int qbase = blockIdx.x * 128 + wr * 32;
    const int vbase = blockIdx.y * 128 + wc * 64;
    const unsigned short* Pb = P + (size_t)b * SEQ * SEQ;

    f32x4 acc[2][4] = {};
#pragma unroll 4
    for (int k0 = 0; k0 < SEQ; k0 += 32) {
        bf16x8 a[2], bb[4];
#pragma unroll
        for (int i = 0; i < 2; ++i)
            a[i] = *(const bf16x8*)(Pb + (size_t)(qbase + i * 16 + lr) * SEQ + k0 + lk * 8);
#pragma unroll
        for (int j = 0; j < 4; ++j)
            bb[j] = *(const bf16x8*)(Vt + (size_t)(vbase + j * 16 + lr) * ROWS + (size_t)b * SEQ + k0 + lk * 8);
#pragma unroll
        for (int i = 0; i < 2; ++i)
#pragma unroll
            for (int j = 0; j < 4; ++j)
                acc[i][j] = __builtin_amdgcn_mfma_f32_16x16x32_bf16(a[i], bb[j], acc[i][j], 0, 0, 0);
    }
    float* O = out + (size_t)b * SEQ * 256;
#pragma unroll
    for (int i = 0; i < 2; ++i)
#pragma unroll
        for (int j = 0; j < 4; ++j)
#pragma unroll
            for (int r = 0; r < 4; ++r) {
                int row = qbase + i * 16 + lk * 4 + r;
                int col = vbase + j * 16 + lr;
                O[(size_t)row * 256 + col] = acc[i][j][r];
            }
}

// ================= PATH B (fallback, R1 kernels) =================
__global__ __launch_bounds__(256) void colsumexp(const unsigned short* __restrict__ Qb,
                                                 const unsigned short* __restrict__ Kb,
                                                 float* __restrict__ lsum) {
    const int l = threadIdx.x & 63;
    const int w = threadIdx.x >> 6;
    const int wr = w >> 1, wc = w & 1;
    const int lr = l & 15, lk = l >> 4;
    const int b = blockIdx.z;
    const int cbase = blockIdx.x * 128 + wc * 64;
    const unsigned short* Q = Qb + (size_t)b * SEQ * 256;
    const unsigned short* K = Kb + (size_t)b * SEQ * 256;

    float csum[4] = {0.f, 0.f, 0.f, 0.f};
    for (int qi = 0; qi < 16; ++qi) {
        const int rbase = blockIdx.y * 2048 + qi * 128 + wr * 64;
        f32x4 acc[4][4] = {};
#pragma unroll
        for (int d0 = 0; d0 < 256; d0 += 32) {
            bf16x8 a[4], bb[4];
#pragma unroll
            for (int i = 0; i < 4; ++i)
                a[i] = *(const bf16x8*)(Q + (size_t)(rbase + i * 16 + lr) * 256 + d0 + lk * 8);
#pragma unroll
            for (int j = 0; j < 4; ++j)
                bb[j] = *(const bf16x8*)(K + (size_t)(cbase + j * 16 + lr) * 256 + d0 + lk * 8);
#pragma unroll
            for (int i = 0; i < 4; ++i)
#pragma unroll
                for (int j = 0; j < 4; ++j)
                    acc[i][j] = __builtin_amdgcn_mfma_f32_16x16x32_bf16(a[i], bb[j], acc[i][j], 0, 0, 0);
        }
#pragma unroll
        for (int j = 0; j < 4; ++j) {
            float s = 0.f;
#pragma unroll
            for (int i = 0; i < 4; ++i)
#pragma unroll
                for (int r = 0; r < 4; ++r)
                    s += __expf(acc[i][j][r] * 0.0625f);
            csum[j] += s;
        }
    }
#pragma unroll
    for (int j = 0; j < 4; ++j) {
        float s = csum[j];
        s += __shfl_xor(s, 16, 64);
        s += __shfl_xor(s, 32, 64);
        if (lk == 0)
            atomicAdd(&lsum[(size_t)b * SEQ + cbase + j * 16 + lr], s);
    }
}

__global__ __launch_bounds__(256) void pv_kernel(const unsigned short* __restrict__ Qb,
                                                 const unsigned short* __restrict__ Kb,
                                                 const unsigned short* __restrict__ Vt,
                                                 float* __restrict__ out) {
    __shared__ unsigned short P[128][72];
    const int l = threadIdx.x & 63;
    const int w = threadIdx.x >> 6;
    const int wr = w >> 1, wc = w & 1;
    const int lr = l & 15, lk = l >> 4;
    const int b = blockIdx.z;
    const int qbase = blockIdx.x * 128;
    const int vbase = blockIdx.y * 128;
    const unsigned short* Q = Qb + (size_t)b * SEQ * 256;
    const unsigned short* K = Kb + (size_t)b * SEQ * 256;
    const unsigned short* V = Vt + (size_t)b * SEQ;

    f32x4 oacc[4][4] = {};
    for (int k0 = 0; k0 < SEQ; k0 += 64) {
        f32x4 sacc[4][2] = {};
#pragma unroll
        for (int d0 = 0; d0 < 256; d0 += 32) {
            bf16x8 a[4], bb[2];
#pragma unroll
            for (int i = 0; i < 4; ++i)
                a[i] = *(const bf16x8*)(Q + (size_t)(qbase + wr * 64 + i * 16 + lr) * 256 + d0 + lk * 8);
#pragma unroll
            for (int j = 0; j < 2; ++j)
                bb[j] = *(const bf16x8*)(K + (size_t)(k0 + wc * 32 + j * 16 + lr) * 256 + d0 + lk * 8);
#pragma unroll
            for (int i = 0; i < 4; ++i)
#pragma unroll
                for (int j = 0; j < 2; ++j)
                    sacc[i][j] = __builtin_amdgcn_mfma_f32_16x16x32_bf16(a[i], bb[j], sacc[i][j], 0, 0, 0);
        }
#pragma unroll
        for (int i = 0; i < 4; ++i)
#pragma unroll
            for (int j = 0; j < 2; ++j)
#pragma unroll
                for (int r = 0; r < 4; ++r) {
                    int row = wr * 64 + i * 16 + lk * 4 + r;
                    int col = wc * 32 + j * 16 + lr;
                    P[row][col] = f2b(__expf(sacc[i][j][r] * 0.0625f));
                }
        __syncthreads();
#pragma unroll
        for (int ks = 0; ks < 2; ++ks) {
            bf16x8 a[4], bb[4];
#pragma unroll
            for (int i = 0; i < 4; ++i)
                a[i] = *(const bf16x8*)(&P[wr * 64 + i * 16 + lr][ks * 32 + lk * 8]);
#pragma unroll
            for (int j = 0; j < 4; ++j)
                bb[j] = *(const bf16x8*)(V + (size_t)(vbase + wc * 64 + j * 16 + lr) * ROWS + k0 + ks * 32 + lk * 8);
#pragma unroll
            for (int i = 0; i < 4; ++i)
#pragma unroll
                for (int j = 0; j < 4; ++j)
                    oacc[i][j] = __builtin_amdgcn_mfma_f32_16x16x32_bf16(a[i], bb[j], oacc[i][j], 0, 0, 0);
        }
        __syncthreads();
    }
    float* O = out + (size_t)b * SEQ * 256;
#pragma unroll
    for (int i = 0; i < 4; ++i)
#pragma unroll
        for (int j = 0; j < 4; ++j)
#pragma unroll
            for (int r = 0; r < 4; ++r) {
                int row = qbase + wr * 64 + i * 16 + lk * 4 + r;
                int col = vbase + wc * 64 + j * 16 + lr;
                O[(size_t)row * 256 + col] = oacc[i][j][r];
            }
}

extern "C" void kernel_launch(void* const* d_in, const int* in_sizes, int n_in,
                              void* d_out, int out_size, void* d_ws, size_t ws_size,
                              hipStream_t stream) {
    const float* x  = (const float*)d_in[0];
    const float* wq = (const float*)d_in[1];
    const float* wk = (const float*)d_in[2];
    const float* wv = (const float*)d_in[3];
    float* out = (float*)d_out;

    char* ws = (char*)d_ws;
    unsigned short* Xb  = (unsigned short*)(ws + 0);
    unsigned short* Qb  = (unsigned short*)(ws + 8388608);
    unsigned short* Kb  = (unsigned short*)(ws + 16777216);
    unsigned short* Vt  = (unsigned short*)(ws + 25165824);
    unsigned short* Wqb = (unsigned short*)(ws + 33554432);
    unsigned short* Wkb = (unsigned short*)(ws + 33685504);
    unsigned short* Wvb = (unsigned short*)(ws + 33816576);
    float*          lsum = (float*)(ws + 33947648);
    unsigned short* Pbuf = (unsigned short*)(ws + 34013184);
    const size_t need_A = 34013184 + (size_t)BATCH * SEQ * SEQ * 2;   // ~168 MB

    const int n_x = ROWS * DIM;      // 4194304
    const int n_w = DIM * DIM;       // 65536

    cast_f32_bf16<<<(n_x + 255) / 256, 256, 0, stream>>>(x, Xb, n_x);
    cast_f32_bf16<<<(n_w + 255) / 256, 256, 0, stream>>>(wq, Wqb, n_w);
    cast_f32_bf16<<<(n_w + 255) / 256, 256, 0, stream>>>(wk, Wkb, n_w);
    cast_f32_bf16<<<(n_w + 255) / 256, 256, 0, stream>>>(wv, Wvb, n_w);

    dim3 gg(ROWS / 128, DIM / 128);   // (128, 2)
    gemm_bt<<<gg, 256, 0, stream>>>(Xb, Wqb, Qb, ROWS, DIM, 0);
    gemm_bt<<<gg, 256, 0, stream>>>(Xb, Wkb, Kb, ROWS, DIM, 0);
    gemm_bt<<<gg, 256, 0, stream>>>(Xb, Wvb, Vt, ROWS, DIM, 1);

    hipMemsetAsync(lsum, 0, (size_t)BATCH * SEQ * sizeof(float), stream);

    if (ws_size >= need_A) {
        // Path A: materialize P, then plain PV GEMM.
        dim3 gs(SEQ / 128, SEQ / 128, BATCH);   // (32, 32, 4) = 4096 blocks
        sp_kernel<<<gs, 256, 0, stream>>>(Qb, Kb, Pbuf, lsum);
        scale_vt<<<(n_x + 255) / 256, 256, 0, stream>>>(Vt, lsum, n_x);
        dim3 gp(SEQ / 128, DIM / 128, BATCH);   // (32, 2, 4) = 256 blocks of 512
        pv_gemm<<<gp, 512, 0, stream>>>(Pbuf, Vt, out);
    } else {
        // Path B: R1 recompute path.
        dim3 gs(SEQ / 128, 2, BATCH);
        colsumexp<<<gs, 256, 0, stream>>>(Qb, Kb, lsum);
        scale_vt<<<(n_x + 255) / 256, 256, 0, stream>>>(Vt, lsum, n_x);
        dim3 gp(SEQ / 128, DIM / 128, BATCH);
        pv_kernel<<<gp, 256, 0, stream>>>(Qb, Kb, Vt, out);
    }
}

// Round 3
// 345.322 us; speedup vs baseline: 1.4115x; 1.0638x over previous
//
#include <hip/hip_runtime.h>
#include <hip/hip_bf16.h>

// Self-attention with softmax over the QUERY axis (dim=1):
//   Q=XWq^T K=XWk^T V=XWv^T ; s = QK^T/16 ; attn[:,q,k] = exp(s)/sum_q exp(s)
//   out = attn @ V
// B=4, S=4096, D=Q_DIM=256.
//
// Path A (ws >= ~168MB): materialize P=exp(s/16) bf16 in ws; PV = plain GEMM
//   with depth-4 register pipeline. Path B: flash-style fallback.

#define BATCH 4
#define SEQ 4096
#define DIM 256
#define ROWS (BATCH * SEQ)   // 16384

typedef __bf16 bf16x8 __attribute__((ext_vector_type(8)));
typedef float f32x4 __attribute__((ext_vector_type(4)));

__device__ __forceinline__ unsigned short f2b(float f) {
    union { float f; unsigned u; } v; v.f = f;
    unsigned u = v.u;
    u += 0x7FFFu + ((u >> 16) & 1u);   // RNE
    return (unsigned short)(u >> 16);
}

__device__ __forceinline__ float b2f(unsigned short h) {
    union { unsigned u; float f; } v; v.u = ((unsigned)h) << 16;
    return v.f;
}

// ---------------- vectorized cast f32 -> bf16 (n multiple of 8) ----------------
__global__ void cast_v8(const float* __restrict__ in,
                        unsigned short* __restrict__ out, int n8) {
    int i = blockIdx.x * blockDim.x + threadIdx.x;
    if (i >= n8) return;
    const float4 f0 = *(const float4*)(in + (size_t)i * 8);
    const float4 f1 = *(const float4*)(in + (size_t)i * 8 + 4);
    union { unsigned short u[8]; bf16x8 v; } o;
    o.u[0] = f2b(f0.x); o.u[1] = f2b(f0.y); o.u[2] = f2b(f0.z); o.u[3] = f2b(f0.w);
    o.u[4] = f2b(f1.x); o.u[5] = f2b(f1.y); o.u[6] = f2b(f1.z); o.u[7] = f2b(f1.w);
    *(bf16x8*)(out + (size_t)i * 8) = o.v;
}

// weights: 3 arrays of 65536 cast in one launch
__global__ void cast_w3(const float* __restrict__ w0, const float* __restrict__ w1,
                        const float* __restrict__ w2, unsigned short* __restrict__ o0,
                        unsigned short* __restrict__ o1, unsigned short* __restrict__ o2) {
    int t = blockIdx.x * blockDim.x + threadIdx.x;   // 3 * 8192
    int arr = t >> 13;
    int i = (t & 8191);
    const float* in = arr == 0 ? w0 : arr == 1 ? w1 : w2;
    unsigned short* out = arr == 0 ? o0 : arr == 1 ? o1 : o2;
    const float4 f0 = *(const float4*)(in + (size_t)i * 8);
    const float4 f1 = *(const float4*)(in + (size_t)i * 8 + 4);
    union { unsigned short u[8]; bf16x8 v; } o;
    o.u[0] = f2b(f0.x); o.u[1] = f2b(f0.y); o.u[2] = f2b(f0.z); o.u[3] = f2b(f0.w);
    o.u[4] = f2b(f1.x); o.u[5] = f2b(f1.y); o.u[6] = f2b(f1.z); o.u[7] = f2b(f1.w);
    *(bf16x8*)(out + (size_t)i * 8) = o.v;
}

// ------- QKV GEMM: z=0 Q, z=1 K, z=2 V(transposed store). out = X(Mx256)*W^T -------
__global__ __launch_bounds__(256) void gemm_qkv(const unsigned short* __restrict__ X,
                                                const unsigned short* __restrict__ Wq,
                                                const unsigned short* __restrict__ Wk,
                                                const unsigned short* __restrict__ Wv,
                                                unsigned short* __restrict__ Qo,
                                                unsigned short* __restrict__ Ko,
                                                unsigned short* __restrict__ Vo) {
    const int z = blockIdx.z;
    const unsigned short* Bw = z == 0 ? Wq : z == 1 ? Wk : Wv;
    unsigned short* out = z == 0 ? Qo : z == 1 ? Ko : Vo;
    const int trans = (z == 2);

    const int l = threadIdx.x & 63;
    const int w = threadIdx.x >> 6;
    const int wr = w >> 1, wc = w & 1;
    const int lr = l & 15, lk = l >> 4;
    const int rbase = blockIdx.x * 128 + wr * 64;
    const int cbase = blockIdx.y * 128 + wc * 64;

    f32x4 acc[4][4] = {};
#pragma unroll
    for (int d0 = 0; d0 < 256; d0 += 32) {
        bf16x8 a[4], b[4];
#pragma unroll
        for (int i = 0; i < 4; ++i)
            a[i] = *(const bf16x8*)(X + (size_t)(rbase + i * 16 + lr) * 256 + d0 + lk * 8);
#pragma unroll
        for (int j = 0; j < 4; ++j)
            b[j] = *(const bf16x8*)(Bw + (size_t)(cbase + j * 16 + lr) * 256 + d0 + lk * 8);
#pragma unroll
        for (int i = 0; i < 4; ++i)
#pragma unroll
            for (int j = 0; j < 4; ++j)
                acc[i][j] = __builtin_amdgcn_mfma_f32_16x16x32_bf16(a[i], b[j], acc[i][j], 0, 0, 0);
    }
#pragma unroll
    for (int i = 0; i < 4; ++i)
#pragma unroll
        for (int j = 0; j < 4; ++j)
#pragma unroll
            for (int r = 0; r < 4; ++r) {
                int row = rbase + i * 16 + lk * 4 + r;
                int col = cbase + j * 16 + lr;
                unsigned short v = f2b(acc[i][j][r]);
                if (!trans) out[(size_t)row * DIM + col] = v;
                else        out[(size_t)col * ROWS + row] = v;
            }
}

// ================= PATH A =================
// s-tile 128q x 128k; P=exp(s/16) -> LDS -> coalesced bf16x8 store to ws;
// column partial sums -> atomicAdd lsum. grid (32 k, 32 q, 4 b), block 256.
__global__ __launch_bounds__(256) void sp_kernel(const unsigned short* __restrict__ Qb,
                                                 const unsigned short* __restrict__ Kb,
                                                 unsigned short* __restrict__ P,
                                                 float* __restrict__ lsum) {
    __shared__ unsigned short Pt[128][136];   // 272B row stride: 16B-aligned, banks shift 4/row
    const int l = threadIdx.x & 63;
    const int w = threadIdx.x >> 6;
    const int wr = w >> 1, wc = w & 1;
    const int lr = l & 15, lk = l >> 4;
    const int b = blockIdx.z;
    const int kb0 = blockIdx.x * 128;
    const int qb0 = blockIdx.y * 128;
    const int kbase = kb0 + wc * 64;
    const int qbase = qb0 + wr * 64;
    const unsigned short* Q = Qb + (size_t)b * SEQ * 256;
    const unsigned short* K = Kb + (size_t)b * SEQ * 256;
    unsigned short* Pb = P + (size_t)b * SEQ * SEQ;

    f32x4 acc[4][4] = {};
#pragma unroll
    for (int d0 = 0; d0 < 256; d0 += 32) {
        bf16x8 a[4], bb[4];
#pragma unroll
        for (int i = 0; i < 4; ++i)
            a[i] = *(const bf16x8*)(Q + (size_t)(qbase + i * 16 + lr) * 256 + d0 + lk * 8);
#pragma unroll
        for (int j = 0; j < 4; ++j)
            bb[j] = *(const bf16x8*)(K + (size_t)(kbase + j * 16 + lr) * 256 + d0 + lk * 8);
#pragma unroll
        for (int i = 0; i < 4; ++i)
#pragma unroll
            for (int j = 0; j < 4; ++j)
                acc[i][j] = __builtin_amdgcn_mfma_f32_16x16x32_bf16(a[i], bb[j], acc[i][j], 0, 0, 0);
    }
#pragma unroll
    for (int j = 0; j < 4; ++j) {
        float cs = 0.f;
#pragma unroll
        for (int i = 0; i < 4; ++i)
#pragma unroll
            for (int r = 0; r < 4; ++r) {
                float v = __expf(acc[i][j][r] * 0.0625f);
                cs += v;
                Pt[wr * 64 + i * 16 + lk * 4 + r][wc * 64 + j * 16 + lr] = f2b(v);
            }
        cs += __shfl_xor(cs, 16, 64);
        cs += __shfl_xor(cs, 32, 64);
        if (lk == 0)
            atomicAdd(&lsum[(size_t)b * SEQ + kbase + j * 16 + lr], cs);
    }
    __syncthreads();
    // cooperative coalesced store: 128 rows x 16 chunks(16B), 8 iters x 256 thr
#pragma unroll
    for (int it = 0; it < 8; ++it) {
        int n = it * 256 + threadIdx.x;
        int row = n >> 4;
        int ch = n & 15;
        *(bf16x8*)(Pb + (size_t)(qb0 + row) * SEQ + kb0 + ch * 8) =
            *(const bf16x8*)(&Pt[row][ch * 8]);
    }
}

// scale Vt rows by 1/l (vectorized x8): Vt[v][b*S+k] *= 1/l[b*S+k]
__global__ void scale_vt(unsigned short* __restrict__ Vt,
                         const float* __restrict__ lsum, int n8) {
    int i = blockIdx.x * blockDim.x + threadIdx.x;
    if (i >= n8) return;
    int col8 = (i & (ROWS / 8 - 1)) * 8;   // column base within [0,ROWS)
    union { unsigned short u[8]; bf16x8 v; } d;
    d.v = *(const bf16x8*)(Vt + (size_t)i * 8);
#pragma unroll
    for (int j = 0; j < 8; ++j)
        d.u[j] = f2b(b2f(d.u[j]) / lsum[col8 + j]);
    *(bf16x8*)(Vt + (size_t)i * 8) = d.v;
}

// PV GEMM: out[b,q,v] = sum_k P[b,q,k] * Vts[v][b*S+k]
// tile 128q x 128v, 512 thr = 8 waves (4x2); depth-4 register pipeline, k-step 32.
__global__ __launch_bounds__(512) void pv_gemm(const unsigned short* __restrict__ P,
                                               const unsigned short* __restrict__ Vt,
                                               float* __restrict__ out) {
    const int l = threadIdx.x & 63;
    const int w = threadIdx.x >> 6;
    const int wr = w >> 1, wc = w & 1;   // 4 q-waves x 2 v-waves
    const int lr = l & 15, lk = l >> 4;
    const int b = blockIdx.z;
    const int qbase = blockIdx.x * 128 + wr * 32;
    const int vbase = blockIdx.y * 128 + wc * 64;
    const unsigned short* Pb = P + (size_t)b * SEQ * SEQ;

    const unsigned short* pA0 = Pb + (size_t)(qbase + lr) * SEQ + lk * 8;
    const unsigned short* pA1 = Pb + (size_t)(qbase + 16 + lr) * SEQ + lk * 8;
    const unsigned short* pV0 = Vt + (size_t)(vbase + 0 + lr) * ROWS + (size_t)b * SEQ + lk * 8;
    const unsigned short* pV1 = Vt + (size_t)(vbase + 16 + lr) * ROWS + (size_t)b * SEQ + lk * 8;
    const unsigned short* pV2 = Vt + (size_t)(vbase + 32 + lr) * ROWS + (size_t)b * SEQ + lk * 8;
    const unsigned short* pV3 = Vt + (size_t)(vbase + 48 + lr) * ROWS + (size_t)b * SEQ + lk * 8;

    bf16x8 a_[4][2], b_[4][4];
#define PVLD(s, k0) do { \
        a_[s][0] = *(const bf16x8*)(pA0 + (k0)); \
        a_[s][1] = *(const bf16x8*)(pA1 + (k0)); \
        b_[s][0] = *(const bf16x8*)(pV0 + (k0)); \
        b_[s][1] = *(const bf16x8*)(pV1 + (k0)); \
        b_[s][2] = *(const bf16x8*)(pV2 + (k0)); \
        b_[s][3] = *(const bf16x8*)(pV3 + (k0)); \
    } while (0)

    f32x4 acc[2][4] = {};
    PVLD(0, 0); PVLD(1, 32); PVLD(2, 64); PVLD(3, 96);
    for (int kt = 0; kt < SEQ; kt += 128) {
#pragma unroll
        for (int s = 0; s < 4; ++s) {
#pragma unroll
            for (int i = 0; i < 2; ++i)
#pragma unroll
                for (int j = 0; j < 4; ++j)
                    acc[i][j] = __builtin_amdgcn_mfma_f32_16x16x32_bf16(a_[s][i], b_[s][j], acc[i][j], 0, 0, 0);
            const int kn = (kt + 128 + s * 32) & (SEQ - 1);   // tail prefetch wraps, unused
            PVLD(s, kn);
        }
    }
#undef PVLD
    float* O = out + (size_t)b * SEQ * 256;
#pragma unroll
    for (int i = 0; i < 2; ++i)
#pragma unroll
        for (int j = 0; j < 4; ++j)
#pragma unroll
            for (int r = 0; r < 4; ++r) {
                int row = qbase + i * 16 + lk * 4 + r;
                int col = vbase + j * 16 + lr;
                O[(size_t)row * 256 + col] = acc[i][j][r];
            }
}

// ================= PATH B (fallback) =================
__global__ __launch_bounds__(256) void colsumexp(const unsigned short* __restrict__ Qb,
                                                 const unsigned short* __restrict__ Kb,
                                                 float* __restrict__ lsum) {
    const int l = threadIdx.x & 63;
    const int w = threadIdx.x >> 6;
    const int wr = w >> 1, wc = w & 1;
    const int lr = l & 15, lk = l >> 4;
    const int b = blockIdx.z;
    const int cbase = blockIdx.x * 128 + wc * 64;
    const unsigned short* Q = Qb + (size_t)b * SEQ * 256;
    const unsigned short* K = Kb + (size_t)b * SEQ * 256;

    float csum[4] = {0.f, 0.f, 0.f, 0.f};
    for (int qi = 0; qi < 16; ++qi) {
        const int rbase = blockIdx.y * 2048 + qi * 128 + wr * 64;
        f32x4 acc[4][4] = {};
#pragma unroll
        for (int d0 = 0; d0 < 256; d0 += 32) {
            bf16x8 a[4], bb[4];
#pragma unroll
            for (int i = 0; i < 4; ++i)
                a[i] = *(const bf16x8*)(Q + (size_t)(rbase + i * 16 + lr) * 256 + d0 + lk * 8);
#pragma unroll
            for (int j = 0; j < 4; ++j)
                bb[j] = *(const bf16x8*)(K + (size_t)(cbase + j * 16 + lr) * 256 + d0 + lk * 8);
#pragma unroll
            for (int i = 0; i < 4; ++i)
#pragma unroll
                for (int j = 0; j < 4; ++j)
                    acc[i][j] = __builtin_amdgcn_mfma_f32_16x16x32_bf16(a[i], bb[j], acc[i][j], 0, 0, 0);
        }
#pragma unroll
        for (int j = 0; j < 4; ++j) {
            float s = 0.f;
#pragma unroll
            for (int i = 0; i < 4; ++i)
#pragma unroll
                for (int r = 0; r < 4; ++r)
                    s += __expf(acc[i][j][r] * 0.0625f);
            csum[j] += s;
        }
    }
#pragma unroll
    for (int j = 0; j < 4; ++j) {
        float s = csum[j];
        s += __shfl_xor(s, 16, 64);
        s += __shfl_xor(s, 32, 64);
        if (lk == 0)
            atomicAdd(&lsum[(size_t)b * SEQ + cbase + j * 16 + lr], s);
    }
}

__global__ __launch_bounds__(256) void pv_kernel(const unsigned short* __restrict__ Qb,
                                                 const unsigned short* __restrict__ Kb,
                                                 const unsigned short* __restrict__ Vt,
                                                 float* __restrict__ out) {
    __shared__ unsigned short Pl[128][72];
    const int l = threadIdx.x & 63;
    const int w = threadIdx.x >> 6;
    const int wr = w >> 1, wc = w & 1;
    const int lr = l & 15, lk = l >> 4;
    const int b = blockIdx.z;
    const int qbase = blockIdx.x * 128;
    const int vbase = blockIdx.y * 128;
    const unsigned short* Q = Qb + (size_t)b * SEQ * 256;
    const unsigned short* K = Kb + (size_t)b * SEQ * 256;
    const unsigned short* V = Vt + (size_t)b * SEQ;

    f32x4 oacc[4][4] = {};
    for (int k0 = 0; k0 < SEQ; k0 += 64) {
        f32x4 sacc[4][2] = {};
#pragma unroll
        for (int d0 = 0; d0 < 256; d0 += 32) {
            bf16x8 a[4], bb[2];
#pragma unroll
            for (int i = 0; i < 4; ++i)
                a[i] = *(const bf16x8*)(Q + (size_t)(qbase + wr * 64 + i * 16 + lr) * 256 + d0 + lk * 8);
#pragma unroll
            for (int j = 0; j < 2; ++j)
                bb[j] = *(const bf16x8*)(K + (size_t)(k0 + wc * 32 + j * 16 + lr) * 256 + d0 + lk * 8);
#pragma unroll
            for (int i = 0; i < 4; ++i)
#pragma unroll
                for (int j = 0; j < 2; ++j)
                    sacc[i][j] = __builtin_amdgcn_mfma_f32_16x16x32_bf16(a[i], bb[j], sacc[i][j], 0, 0, 0);
        }
#pragma unroll
        for (int i = 0; i < 4; ++i)
#pragma unroll
            for (int j = 0; j < 2; ++j)
#pragma unroll
                for (int r = 0; r < 4; ++r)
                    Pl[wr * 64 + i * 16 + lk * 4 + r][wc * 32 + j * 16 + lr] =
                        f2b(__expf(sacc[i][j][r] * 0.0625f));
        __syncthreads();
#pragma unroll
        for (int ks = 0; ks < 2; ++ks) {
            bf16x8 a[4], bb[4];
#pragma unroll
            for (int i = 0; i < 4; ++i)
                a[i] = *(const bf16x8*)(&Pl[wr * 64 + i * 16 + lr][ks * 32 + lk * 8]);
#pragma unroll
            for (int j = 0; j < 4; ++j)
                bb[j] = *(const bf16x8*)(V + (size_t)(vbase + wc * 64 + j * 16 + lr) * ROWS + k0 + ks * 32 + lk * 8);
#pragma unroll
            for (int i = 0; i < 4; ++i)
#pragma unroll
                for (int j = 0; j < 4; ++j)
                    oacc[i][j] = __builtin_amdgcn_mfma_f32_16x16x32_bf16(a[i], bb[j], oacc[i][j], 0, 0, 0);
        }
        __syncthreads();
    }
    float* O = out + (size_t)b * SEQ * 256;
#pragma unroll
    for (int i = 0; i < 4; ++i)
#pragma unroll
        for (int j = 0; j < 4; ++j)
#pragma unroll
            for (int r = 0; r < 4; ++r) {
                int row = qbase + wr * 64 + i * 16 + lk * 4 + r;
                int col = vbase + wc * 64 + j * 16 + lr;
                O[(size_t)row * 256 + col] = oacc[i][j][r];
            }
}

extern "C" void kernel_launch(void* const* d_in, const int* in_sizes, int n_in,
                              void* d_out, int out_size, void* d_ws, size_t ws_size,
                              hipStream_t stream) {
    const float* x  = (const float*)d_in[0];
    const float* wq = (const float*)d_in[1];
    const float* wk = (const float*)d_in[2];
    const float* wv = (const float*)d_in[3];
    float* out = (float*)d_out;

    char* ws = (char*)d_ws;
    unsigned short* Xb  = (unsigned short*)(ws + 0);
    unsigned short* Qb  = (unsigned short*)(ws + 8388608);
    unsigned short* Kb  = (unsigned short*)(ws + 16777216);
    unsigned short* Vt  = (unsigned short*)(ws + 25165824);
    unsigned short* Wqb = (unsigned short*)(ws + 33554432);
    unsigned short* Wkb = (unsigned short*)(ws + 33685504);
    unsigned short* Wvb = (unsigned short*)(ws + 33816576);
    float*          lsum = (float*)(ws + 33947648);
    unsigned short* Pbuf = (unsigned short*)(ws + 34013184);
    const size_t need_A = 34013184 + (size_t)BATCH * SEQ * SEQ * 2;   // ~168 MB

    const int n_x = ROWS * DIM;      // 4194304

    cast_v8<<<(n_x / 8 + 255) / 256, 256, 0, stream>>>(x, Xb, n_x / 8);
    cast_w3<<<(3 * 8192 + 255) / 256, 256, 0, stream>>>(wq, wk, wv, Wqb, Wkb, Wvb);

    dim3 gg(ROWS / 128, DIM / 128, 3);   // (128, 2, 3)
    gemm_qkv<<<gg, 256, 0, stream>>>(Xb, Wqb, Wkb, Wvb, Qb, Kb, Vt);

    hipMemsetAsync(lsum, 0, (size_t)BATCH * SEQ * sizeof(float), stream);

    if (ws_size >= need_A) {
        dim3 gs(SEQ / 128, SEQ / 128, BATCH);   // (32, 32, 4)
        sp_kernel<<<gs, 256, 0, stream>>>(Qb, Kb, Pbuf, lsum);
        scale_vt<<<(n_x / 8 + 255) / 256, 256, 0, stream>>>(Vt, lsum, n_x / 8);
        dim3 gp(SEQ / 128, DIM / 128, BATCH);   // (32, 2, 4)
        pv_gemm<<<gp, 512, 0, stream>>>(Pbuf, Vt, out);
    } else {
        dim3 gs(SEQ / 128, 2, BATCH);
        colsumexp<<<gs, 256, 0, stream>>>(Qb, Kb, lsum);
        scale_vt<<<(n_x / 8 + 255) / 256, 256, 0, stream>>>(Vt, lsum, n_x / 8);
        dim3 gp(SEQ / 128, DIM / 128, BATCH);
        pv_kernel<<<gp, 256, 0, stream>>>(Qb, Kb, Vt, out);
    }
}